// Round 7
// baseline (3808.019 us; speedup 1.0000x reference)
//
#include <hip/hip_runtime.h>

// ---------------- problem constants ----------------
#define NB    256
#define TLEN  1632
#define HIDC  64
#define CBD   512
#define NTOK  1024
#define T2L   816
#define T4L   408
#define MTOK  (NB*T4L)     // 104448
#define M2TOK (NB*T2L)     // 208896
#define MOUT  (NB*TLEN)    // 417792
#define TAU   0.05f

// d_out flat offsets (floats)
#define DO_OUT    ((size_t)0)
#define DO_RECON  ((size_t)417792)
#define DO_IDX    ((size_t)417795)
#define DO_QUANT  ((size_t)626691)

typedef unsigned short u16;
typedef __attribute__((ext_vector_type(8))) short short8;
typedef __attribute__((ext_vector_type(4))) float f32x4;

// ---------------- workspace layout (float units, all offsets %4==0) ----------------
static constexpr size_t OFF_XR  = 0;                         // MTOK*512 f32
static constexpr size_t OFF_H1  = OFF_XR + (size_t)MTOK*512; // 13369344
static constexpr size_t OFF_H2  = OFF_H1 + (size_t)NB*T2L*64;
static constexpr size_t OFF_BE2 = OFF_H2 + (size_t)NB*T4L*64;
static constexpr size_t OFF_BD1 = OFF_BE2 + 8192;
static constexpr size_t OFF_BD2 = OFF_BD1 + 65536;
static constexpr size_t OFF_BX1 = OFF_BD2 + 8192;
static constexpr size_t OFF_BX2 = OFF_BX1 + 128;
static constexpr size_t OFF_ZB  = OFF_BX2 + 128;
static constexpr size_t OFF_C2  = OFF_ZB + 128;
static constexpr size_t OFF_R2  = OFF_C2 + 2048;
static constexpr size_t OFF_SLOT= OFF_R2 + MTOK;
static constexpr size_t OFF_IDXI= OFF_SLOT + 1536;           // MTOK*2 ints
static constexpr size_t OFF_KEYS= OFF_IDXI + (size_t)MTOK*2; // 2*MTOK u64
static constexpr size_t OFF_FC  = OFF_KEYS + (size_t)MTOK*4;
static constexpr size_t OFF_FLAG= OFF_FC + 4;                // 2*MTOK ints
static constexpr size_t OFF_CBH = OFF_FLAG + (size_t)MTOK*2; // 2048*512 u16 = 524288 f
static constexpr size_t OFF_CBL = OFF_CBH + 524288;
static constexpr size_t OFF_P0  = OFF_CBL + 524288;          // 1024*128 f32
static constexpr size_t OFF_P1  = OFF_P0 + 131072;

// ---------------- helpers ----------------
__device__ inline unsigned long long shfl_xor_u64_w16(unsigned long long v, int m) {
    unsigned lo = (unsigned)v, hi = (unsigned)(v >> 32);
    lo = __shfl_xor(lo, m, 16);
    hi = __shfl_xor(hi, m, 16);
    return (((unsigned long long)hi) << 32) | lo;
}
__device__ inline unsigned long long packkey(float d, int n) {
    unsigned u = __float_as_uint(d);
    u = (u & 0x80000000u) ? ~u : (u | 0x80000000u);
    return (((unsigned long long)u) << 32) | (unsigned)n;
}
__device__ inline float unpackd(unsigned long long k) {
    unsigned u = (unsigned)(k >> 32);
    u = (u & 0x80000000u) ? (u & 0x7fffffffu) : ~u;
    return __uint_as_float(u);
}
__device__ inline void merge2(unsigned long long& k1, unsigned long long& k2,
                              unsigned long long o1, unsigned long long o2) {
    unsigned long long n1 = (k1 < o1) ? k1 : o1;
    unsigned long long hi = (k1 < o1) ? o1 : k1;
    unsigned long long cand = (k1 <= o1) ? k2 : o2;
    unsigned long long n2 = (hi < cand) ? hi : cand;
    k1 = n1; k2 = n2;
}
// split float4 -> hi/lo bf16 packed as uint2 each (4 shorts)
__device__ inline void split4(float4 v, uint2& h, uint2& l) {
    unsigned b0 = __float_as_uint(v.x), b1 = __float_as_uint(v.y),
             b2 = __float_as_uint(v.z), b3 = __float_as_uint(v.w);
    float l0 = v.x - __uint_as_float(b0 & 0xFFFF0000u);
    float l1 = v.y - __uint_as_float(b1 & 0xFFFF0000u);
    float l2 = v.z - __uint_as_float(b2 & 0xFFFF0000u);
    float l3 = v.w - __uint_as_float(b3 & 0xFFFF0000u);
    h.x = (b0 >> 16) | (b1 & 0xFFFF0000u);
    h.y = (b2 >> 16) | (b3 & 0xFFFF0000u);
    l.x = (__float_as_uint(l0) >> 16) | (__float_as_uint(l1) & 0xFFFF0000u);
    l.y = (__float_as_uint(l2) >> 16) | (__float_as_uint(l3) & 0xFFFF0000u);
}

// ---------------- weight prep ----------------
__global__ void prep_kernel(const float* __restrict__ We2, const float* __restrict__ Wtd1,
                            const float* __restrict__ Wtd2, const float* __restrict__ bd1,
                            const float* __restrict__ bd2,
                            float* __restrict__ Be2, float* __restrict__ Bd1,
                            float* __restrict__ Bd2, float* __restrict__ bx1, float* __restrict__ bx2) {
    int i = blockIdx.x * blockDim.x + threadIdx.x;
    int stride = gridDim.x * blockDim.x;
    for (int x = i; x < 64 * 128; x += stride) {
        int c = x >> 7, k = x & 127;
        Be2[x] = We2[c * 128 + ((k & 63) << 1) + (k >> 6)];
    }
    for (int x = i; x < 128 * 512; x += stride) {
        int n = x >> 9, k = x & 511;
        Bd1[x] = Wtd1[k * 128 + n];
    }
    for (int x = i; x < 128 * 64; x += stride) {
        int n = x >> 6, k = x & 63;
        Bd2[x] = Wtd2[k * 128 + n];
    }
    for (int x = i; x < 128; x += stride) { bx1[x] = bd1[x >> 1]; bx2[x] = bd2[x >> 1]; }
}

// ---------------- codebook split to planar bf16 hi/lo ----------------
__global__ void split_cb_kernel(const float* __restrict__ cbs, u16* __restrict__ cbh, u16* __restrict__ cbl) {
    size_t t = (size_t)blockIdx.x * 256 + threadIdx.x;   // over 2048*512/4
    float4 v = *(const float4*)(cbs + t * 4);
    uint2 h, l; split4(v, h, l);
    *(uint2*)&cbh[t * 4] = h;
    *(uint2*)&cbl[t * 4] = l;
}

// ---------------- row sum-of-squares ----------------
__global__ void rownorm_kernel(const float* __restrict__ X, float* __restrict__ out, int rows) {
    int w = (blockIdx.x * blockDim.x + threadIdx.x) >> 6;
    int lane = threadIdx.x & 63;
    if (w >= rows) return;
    const float* r = X + (size_t)w * 512;
    float4 a = *(const float4*)(r + lane * 8);
    float4 b = *(const float4*)(r + lane * 8 + 4);
    float s = a.x*a.x + a.y*a.y + a.z*a.z + a.w*a.w + b.x*b.x + b.y*b.y + b.z*b.z + b.w*b.w;
    #pragma unroll
    for (int o = 32; o > 0; o >>= 1) s += __shfl_down(s, o, 64);
    if (lane == 0) out[w] = s;
}

// ---------------- encoder conv1 ----------------
__global__ void enc1_kernel(const float* __restrict__ img, const float* __restrict__ W,
                            const float* __restrict__ bias, float* __restrict__ h1) {
    int idx = blockIdx.x * 256 + threadIdx.x;
    int c = idx & 63;
    int t = (idx >> 6) % T2L;
    int b = idx / (64 * T2L);
    float v = W[c * 2] * img[(size_t)b * TLEN + 2 * t] +
              W[c * 2 + 1] * img[(size_t)b * TLEN + 2 * t + 1] + bias[c];
    h1[idx] = fmaxf(v, 0.f);
}

// ---------------- generic NT SGEMM ----------------
__global__ __launch_bounds__(256) void gemm_nt(const float* __restrict__ A, const float* __restrict__ Bw,
                        const float* __restrict__ bias, float* __restrict__ C,
                        int M, int N, int K, int amode, int cmode, int relu) {
    __shared__ float As[32][132];
    __shared__ float Bs[32][68];
    int m0 = blockIdx.x * 128;
    int n0 = blockIdx.y * 64;
    int tid = threadIdx.x;
    int tx = tid & 15;
    int ty = tid >> 4;
    float acc[8][4];
    #pragma unroll
    for (int i = 0; i < 8; ++i)
        #pragma unroll
        for (int j = 0; j < 4; ++j) acc[i][j] = 0.f;

    for (int k0 = 0; k0 < K; k0 += 32) {
        #pragma unroll
        for (int i = 0; i < 4; ++i) {
            int idx = tid + i * 256;
            int row = idx >> 3;
            int kq = idx & 7;
            int m = m0 + row;
            size_t base;
            if (amode == 0) base = (size_t)m * K;
            else            base = (size_t)(((m / T4L) * T2L + 2 * (m % T4L)) * 64);
            float4 v = *(const float4*)(A + base + k0 + kq * 4);
            int kk = kq * 4;
            As[kk + 0][row] = v.x; As[kk + 1][row] = v.y;
            As[kk + 2][row] = v.z; As[kk + 3][row] = v.w;
        }
        #pragma unroll
        for (int i = 0; i < 2; ++i) {
            int idx = tid + i * 256;
            int row = idx >> 3;
            int kq = idx & 7;
            float4 v = *(const float4*)(Bw + (size_t)(n0 + row) * K + k0 + kq * 4);
            int kk = kq * 4;
            Bs[kk + 0][row] = v.x; Bs[kk + 1][row] = v.y;
            Bs[kk + 2][row] = v.z; Bs[kk + 3][row] = v.w;
        }
        __syncthreads();
        #pragma unroll
        for (int kk = 0; kk < 32; ++kk) {
            float a[8], bf[4];
            float4 a0 = *(const float4*)&As[kk][ty * 8];
            float4 a1 = *(const float4*)&As[kk][ty * 8 + 4];
            a[0]=a0.x; a[1]=a0.y; a[2]=a0.z; a[3]=a0.w;
            a[4]=a1.x; a[5]=a1.y; a[6]=a1.z; a[7]=a1.w;
            float4 b0 = *(const float4*)&Bs[kk][tx * 4];
            bf[0]=b0.x; bf[1]=b0.y; bf[2]=b0.z; bf[3]=b0.w;
            #pragma unroll
            for (int i = 0; i < 8; ++i)
                #pragma unroll
                for (int j = 0; j < 4; ++j) acc[i][j] += a[i] * bf[j];
        }
        __syncthreads();
    }
    #pragma unroll
    for (int i = 0; i < 8; ++i) {
        int m = m0 + ty * 8 + i;
        if (cmode == 0) {
            float4 v;
            v.x = acc[i][0] + bias[n0 + tx * 4 + 0];
            v.y = acc[i][1] + bias[n0 + tx * 4 + 1];
            v.z = acc[i][2] + bias[n0 + tx * 4 + 2];
            v.w = acc[i][3] + bias[n0 + tx * 4 + 3];
            if (relu) { v.x=fmaxf(v.x,0.f); v.y=fmaxf(v.y,0.f); v.z=fmaxf(v.z,0.f); v.w=fmaxf(v.w,0.f); }
            *(float4*)(C + (size_t)m * N + n0 + tx * 4) = v;
        } else {
            int Tin = T2L;
            int Texp = 2 * Tin;
            int bb = m / Tin, t = m % Tin;
            #pragma unroll
            for (int j = 0; j < 4; ++j) {
                int n = n0 + tx * 4 + j;
                float v = acc[i][j] + bias[n];
                if (relu) v = fmaxf(v, 0.f);
                size_t off = (size_t)((bb * Texp + 2 * t + (n & 1)) * 64 + (n >> 1));
                C[off] = v;
            }
        }
    }
}

// ---------------- VQ: A-stationary split-bf16 MFMA + in-register global top-2 ----------------
// Block: 32 tokens, full K=512 A hi/lo resident in LDS (64 KB, XOR-swizzled 16B chunks).
// Streams pre-split codebook from L2 as B-fragments. 4 waves = 2 m-tiles x 2 n-halves.
__global__ __launch_bounds__(256) void vq_mfma_top2(
    const float* __restrict__ A, const u16* __restrict__ cbh, const u16* __restrict__ cbl,
    const float* __restrict__ c2, const float* __restrict__ r2,
    unsigned long long* __restrict__ keybuf, int* __restrict__ fc, int* __restrict__ flaglist)
{
    __shared__ u16 Ah[32 * 512];
    __shared__ u16 Al[32 * 512];
    int tid = threadIdx.x;
    int m0 = blockIdx.x * 32;
    int lane = tid & 63, wid = tid >> 6;
    int lm = lane & 15, quad = lane >> 4;
    int mt = wid & 1, nh = wid >> 1;

    // ---- stage + split A (32 rows x 512), swizzled chunk = (c ^ (row&7)) ----
    {
        int r0 = tid >> 7;               // 0..1
        int col = (tid & 127) * 4;       // multiple of 4
        int ch = col >> 3, hf = col & 7; // 16B chunk, half offset {0,4}
        for (int i = 0; i < 16; ++i) {
            int row = i * 2 + r0;
            float4 v = *(const float4*)(A + (size_t)(m0 + row) * 512 + col);
            uint2 h, l; split4(v, h, l);
            int off = row * 512 + ((ch ^ (row & 7)) << 3) + hf;
            *(uint2*)&Ah[off] = h;
            *(uint2*)&Al[off] = l;
        }
    }
    __syncthreads();

    float rr[4];
    #pragma unroll
    for (int r = 0; r < 4; ++r) rr[r] = r2[m0 + mt * 16 + quad * 4 + r];

    unsigned long long t1[4], t2[4];
    #pragma unroll
    for (int r = 0; r < 4; ++r) { t1[r] = ~0ull; t2[r] = ~0ull; }

    for (int nc = 0; nc < 16; ++nc) {
        int nbase = nc * 64 + nh * 32;
        f32x4 acc0 = {0.f,0.f,0.f,0.f}, acc1 = {0.f,0.f,0.f,0.f};
        size_t boff = ((size_t)(nbase + lm)) * 512 + quad * 8;
        short8 bh0 = *(const short8*)(cbh + boff);
        short8 bl0 = *(const short8*)(cbl + boff);
        short8 bh1 = *(const short8*)(cbh + boff + 16 * 512);
        short8 bl1 = *(const short8*)(cbl + boff + 16 * 512);
        #pragma unroll
        for (int ks = 0; ks < 16; ++ks) {
            short8 nh0, nl0, nh1, nl1;
            if (ks < 15) {
                size_t bo = boff + (ks + 1) * 32;
                nh0 = *(const short8*)(cbh + bo);
                nl0 = *(const short8*)(cbl + bo);
                nh1 = *(const short8*)(cbh + bo + 16 * 512);
                nl1 = *(const short8*)(cbl + bo + 16 * 512);
            }
            int arow = mt * 16 + lm;
            int c = ks * 4 + quad;
            int aoff = arow * 512 + ((c ^ (arow & 7)) << 3);
            short8 ah = *(const short8*)&Ah[aoff];
            short8 al = *(const short8*)&Al[aoff];
            acc0 = __builtin_amdgcn_mfma_f32_16x16x32_bf16(al, bh0, acc0, 0, 0, 0);
            acc0 = __builtin_amdgcn_mfma_f32_16x16x32_bf16(ah, bl0, acc0, 0, 0, 0);
            acc0 = __builtin_amdgcn_mfma_f32_16x16x32_bf16(ah, bh0, acc0, 0, 0, 0);
            acc1 = __builtin_amdgcn_mfma_f32_16x16x32_bf16(al, bh1, acc1, 0, 0, 0);
            acc1 = __builtin_amdgcn_mfma_f32_16x16x32_bf16(ah, bl1, acc1, 0, 0, 0);
            acc1 = __builtin_amdgcn_mfma_f32_16x16x32_bf16(ah, bh1, acc1, 0, 0, 0);
            bh0 = nh0; bl0 = nl0; bh1 = nh1; bl1 = nl1;
        }
        float c2a = c2[nbase + lm];
        float c2b = c2[nbase + 16 + lm];
        #pragma unroll
        for (int r = 0; r < 4; ++r) {
            float d0 = (rr[r] - 2.0f * acc0[r]) + c2a;
            float d1 = (rr[r] - 2.0f * acc1[r]) + c2b;
            unsigned long long ka = packkey(d0, nbase + lm);
            unsigned long long kb = packkey(d1, nbase + 16 + lm);
            unsigned long long k1 = (ka < kb) ? ka : kb;
            unsigned long long k2 = (ka < kb) ? kb : ka;
            #pragma unroll
            for (int s = 1; s < 16; s <<= 1) {
                unsigned long long o1 = shfl_xor_u64_w16(k1, s);
                unsigned long long o2 = shfl_xor_u64_w16(k2, s);
                merge2(k1, k2, o1, o2);
            }
            merge2(t1[r], t2[r], k1, k2);
        }
    }
    // cross-n-half merge via LDS scratch (reuse Ah), then write keybuf + flags
    __syncthreads();
    unsigned long long* scr = (unsigned long long*)Ah;
    if (nh == 1 && lm == 0) {
        #pragma unroll
        for (int r = 0; r < 4; ++r) {
            int rl = mt * 16 + quad * 4 + r;
            scr[rl * 2] = t1[r]; scr[rl * 2 + 1] = t2[r];
        }
    }
    __syncthreads();
    if (nh == 0 && lm == 0) {
        #pragma unroll
        for (int r = 0; r < 4; ++r) {
            int rl = mt * 16 + quad * 4 + r;
            merge2(t1[r], t2[r], scr[rl * 2], scr[rl * 2 + 1]);
            int m = m0 + rl;
            keybuf[m] = t1[r];
            if (unpackd(t2[r]) - unpackd(t1[r]) < TAU) {
                int pos = atomicAdd(fc, 1);
                flaglist[pos] = m;
            }
        }
    }
}

// ---------------- rescue: exact fp32 argmin for flagged tokens ----------------
__global__ void vq_rescue(const float* __restrict__ xr, const float* __restrict__ cb,
                          const float* __restrict__ c2, const float* __restrict__ r2,
                          const int* __restrict__ fc, const int* __restrict__ flaglist,
                          unsigned long long* __restrict__ keybuf) {
    __shared__ unsigned long long red[4];
    int cnt = *fc;
    int lane = threadIdx.x & 63, wid = threadIdx.x >> 6;
    for (int f = blockIdx.x; f < cnt; f += gridDim.x) {
        int m = flaglist[f];
        float4 rv0 = *(const float4*)(xr + (size_t)m * 512 + lane * 8);
        float4 rv1 = *(const float4*)(xr + (size_t)m * 512 + lane * 8 + 4);
        float rr = r2[m];
        unsigned long long best = ~0ull;
        for (int c = wid * 256; c < wid * 256 + 256; ++c) {
            const float* cp = cb + (size_t)c * 512 + lane * 8;
            float4 c0 = *(const float4*)cp;
            float4 c1 = *(const float4*)(cp + 4);
            float p = rv0.x*c0.x + rv0.y*c0.y + rv0.z*c0.z + rv0.w*c0.w
                    + rv1.x*c1.x + rv1.y*c1.y + rv1.z*c1.z + rv1.w*c1.w;
            #pragma unroll
            for (int s = 1; s < 64; s <<= 1) p += __shfl_xor(p, s, 64);
            unsigned long long k = packkey((rr - 2.0f * p) + c2[c], c);
            if (k < best) best = k;
        }
        if (lane == 0) red[wid] = best;
        __syncthreads();
        if (threadIdx.x == 0) {
            unsigned long long b = red[0];
            if (red[1] < b) b = red[1];
            if (red[2] < b) b = red[2];
            if (red[3] < b) b = red[3];
            keybuf[m] = b;
        }
        __syncthreads();
    }
}

// ---------------- VQ apply (wave per token) ----------------
__global__ void vq_apply(const float* __restrict__ cb, const unsigned long long* __restrict__ keybuf,
                         float* __restrict__ R, float* __restrict__ r2,
                         float* __restrict__ idx_f, int* __restrict__ idx_i,
                         float* __restrict__ slots, int q, int write_r) {
    int tid = threadIdx.x;
    int lane = tid & 63;
    int m = blockIdx.x * 4 + (tid >> 6);
    unsigned idx = (unsigned)(keybuf[m] & 0xFFFFFFFFull);
    const float* c = cb + (size_t)idx * 512 + lane * 8;
    float* r = R + (size_t)m * 512 + lane * 8;
    float4 r0 = *(const float4*)r, r1 = *(const float4*)(r + 4);
    float4 c0 = *(const float4*)c, c1 = *(const float4*)(c + 4);
    r0.x -= c0.x; r0.y -= c0.y; r0.z -= c0.z; r0.w -= c0.w;
    r1.x -= c1.x; r1.y -= c1.y; r1.z -= c1.z; r1.w -= c1.w;
    if (write_r) { *(float4*)r = r0; *(float4*)(r + 4) = r1; }
    float s = r0.x*r0.x + r0.y*r0.y + r0.z*r0.z + r0.w*r0.w
            + r1.x*r1.x + r1.y*r1.y + r1.z*r1.z + r1.w*r1.w;
    #pragma unroll
    for (int o = 32; o > 0; o >>= 1) s += __shfl_down(s, o, 64);
    if (lane == 0) {
        if (write_r) r2[m] = s;
        atomicAdd(&slots[512 + q * 512 + (m & 511)], s);
        idx_f[(size_t)m * 2 + q] = (float)idx;
        idx_i[m * 2 + q] = (int)idx;
    }
}

// ---------------- quantized output (channel-major) via LDS transpose ----------------
__global__ void quant_out_kernel(const float* __restrict__ cb0, const float* __restrict__ cb1,
                                 const int* __restrict__ idxi, float* __restrict__ out4) {
    __shared__ float buf[64][129];
    __shared__ int i0s[64], i1s[64];
    int b = blockIdx.x;
    int t0 = blockIdx.y * 64;
    int c0 = blockIdx.z * 128;
    int tid = threadIdx.x;
    if (tid < 64) {
        int t = t0 + tid;
        int i0 = 0, i1 = 0;
        if (t < T4L) { i0 = idxi[(b * T4L + t) * 2]; i1 = idxi[(b * T4L + t) * 2 + 1]; }
        i0s[tid] = i0; i1s[tid] = i1;
    }
    __syncthreads();
    int cl = tid & 127, th = tid >> 7;
    for (int t = th; t < 64; t += 2) {
        if (t0 + t < T4L)
            buf[t][cl] = cb0[(size_t)i0s[t] * 512 + c0 + cl] + cb1[(size_t)i1s[t] * 512 + c0 + cl];
    }
    __syncthreads();
    int lane = tid & 63, ch = tid >> 6;
    for (int cc = ch; cc < 128; cc += 4) {
        int t = t0 + lane;
        if (t < T4L) out4[((size_t)b * 512 + c0 + cc) * T4L + t] = buf[lane][cc];
    }
}

// ---------------- decoder stage-1 via code tables: d1 = ReLU(P0[i0]+P1[i1]+b) ----------------
__global__ void d1_gather_kernel(const float* __restrict__ P0, const float* __restrict__ P1,
                                 const int* __restrict__ idxi, const float* __restrict__ bx1,
                                 float* __restrict__ d1) {
    int x = blockIdx.x * 256 + threadIdx.x;   // over MTOK*128
    int n = x & 127;
    int m = x >> 7;
    int b = m / T4L, t = m % T4L;
    int i0 = idxi[m * 2], i1 = idxi[m * 2 + 1];
    float v = P0[i0 * 128 + n] + P1[i1 * 128 + n] + bx1[n];
    v = fmaxf(v, 0.f);
    d1[((size_t)(b * T2L + 2 * t + (n & 1))) * 64 + (n >> 1)] = v;
}

// ---------------- final 1x1 conv + recon loss ----------------
__global__ void dec_final_kernel(const float* __restrict__ d2buf, const float* __restrict__ W,
                                 const float* __restrict__ bb, const float* __restrict__ img,
                                 float* __restrict__ out, float* __restrict__ slots) {
    __shared__ float red[256];
    int tok = blockIdx.x * 256 + threadIdx.x;
    float acc = bb[0];
    const float* row = d2buf + (size_t)tok * 64;
    #pragma unroll
    for (int i = 0; i < 16; ++i) {
        float4 v = *(const float4*)(row + i * 4);
        float4 w = *(const float4*)(W + i * 4);
        acc += v.x * w.x + v.y * w.y + v.z * w.z + v.w * w.w;
    }
    out[tok] = acc;
    float d = img[tok] - acc;
    red[threadIdx.x] = d * d; __syncthreads();
    for (int s = 128; s > 0; s >>= 1) { if (threadIdx.x < s) red[threadIdx.x] += red[threadIdx.x + s]; __syncthreads(); }
    if (threadIdx.x == 0) atomicAdd(&slots[blockIdx.x & 511], red[0]);
}

// ---------------- finalize losses ----------------
__global__ void finalize_kernel(const float* __restrict__ slots, float* __restrict__ out_scalars) {
    __shared__ float red[256];
    int tid = threadIdx.x;
    for (int which = 0; which < 3; ++which) {
        float s = slots[which * 512 + tid] + slots[which * 512 + tid + 256];
        red[tid] = s; __syncthreads();
        for (int st = 128; st > 0; st >>= 1) { if (tid < st) red[tid] += red[tid + st]; __syncthreads(); }
        if (tid == 0) {
            float denom = (which == 0) ? (float)MOUT : (float)((size_t)MTOK * 512);
            out_scalars[which] = red[0] / denom;
        }
        __syncthreads();
    }
}

// ---------------- launch ----------------
extern "C" void kernel_launch(void* const* d_in, const int* in_sizes, int n_in,
                              void* d_out, int out_size, void* d_ws, size_t ws_size,
                              hipStream_t stream) {
    const float* img  = (const float*)d_in[0];
    const float* We1  = (const float*)d_in[1];
    const float* be1  = (const float*)d_in[2];
    const float* We2  = (const float*)d_in[3];
    const float* be2  = (const float*)d_in[4];
    const float* We3  = (const float*)d_in[5];
    const float* be3  = (const float*)d_in[6];
    const float* cbs  = (const float*)d_in[7];
    const float* Wtd1 = (const float*)d_in[8];
    const float* bd1  = (const float*)d_in[9];
    const float* Wtd2 = (const float*)d_in[10];
    const float* bd2  = (const float*)d_in[11];
    const float* Wd3  = (const float*)d_in[12];
    const float* bd3  = (const float*)d_in[13];

    float* w = (float*)d_ws;
    float* xr   = w + OFF_XR;
    float* h1   = w + OFF_H1;
    float* h2   = w + OFF_H2;
    float* Be2  = w + OFF_BE2;
    float* Bd1  = w + OFF_BD1;
    float* Bd2  = w + OFF_BD2;
    float* bx1  = w + OFF_BX1;
    float* bx2  = w + OFF_BX2;
    float* zerob= w + OFF_ZB;
    float* c2   = w + OFF_C2;
    float* r2   = w + OFF_R2;
    float* slots= w + OFF_SLOT;
    int*   idxi = (int*)(w + OFF_IDXI);
    unsigned long long* keys = (unsigned long long*)(w + OFF_KEYS);
    int*   fc   = (int*)(w + OFF_FC);
    int*   flag = (int*)(w + OFF_FLAG);
    u16*   cbh  = (u16*)(w + OFF_CBH);
    u16*   cbl  = (u16*)(w + OFF_CBL);
    float* P0   = w + OFF_P0;
    float* P1   = w + OFF_P1;

    float* outp = (float*)d_out;
    float* out0   = outp + DO_OUT;
    float* oscal  = outp + DO_RECON;
    float* idxf   = outp + DO_IDX;
    float* qout   = outp + DO_QUANT;

    hipMemsetAsync(slots, 0, 1536 * sizeof(float), stream);
    hipMemsetAsync(fc, 0, 2 * sizeof(int), stream);
    hipMemsetAsync(zerob, 0, 128 * sizeof(float), stream);

    prep_kernel<<<64, 256, 0, stream>>>(We2, Wtd1, Wtd2, bd1, bd2, Be2, Bd1, Bd2, bx1, bx2);
    split_cb_kernel<<<1024, 256, 0, stream>>>(cbs, cbh, cbl);
    rownorm_kernel<<<(2048 * 64) / 256, 256, 0, stream>>>(cbs, c2, 2048);

    const float* cb1p = cbs + (size_t)NTOK * CBD;

    // decoder stage-1 code tables: P = cb . Bd1^T
    gemm_nt<<<dim3(8, 2), 256, 0, stream>>>(cbs,  Bd1, zerob, P0, 1024, 128, 512, 0, 0, 0);
    gemm_nt<<<dim3(8, 2), 256, 0, stream>>>(cb1p, Bd1, zerob, P1, 1024, 128, 512, 0, 0, 0);

    // encoder
    enc1_kernel<<<(NB * T2L * HIDC) / 256, 256, 0, stream>>>(img, We1, be1, h1);
    gemm_nt<<<dim3(MTOK / 128, 1), 256, 0, stream>>>(h1, Be2, be2, h2, MTOK, 64, 128, 1, 0, 1);
    gemm_nt<<<dim3(MTOK / 128, 8), 256, 0, stream>>>(h2, We3, be3, xr, MTOK, 512, 64, 0, 0, 0);
    rownorm_kernel<<<((size_t)MTOK * 64) / 256, 256, 0, stream>>>(xr, r2, MTOK);

    // residual VQ, q = 0
    vq_mfma_top2<<<MTOK / 32, 256, 0, stream>>>(xr, cbh, cbl, c2, r2, keys, fc + 0, flag);
    vq_rescue<<<1024, 256, 0, stream>>>(xr, cbs, c2, r2, fc + 0, flag, keys);
    vq_apply<<<MTOK / 4, 256, 0, stream>>>(cbs, keys, xr, r2, idxf, idxi, slots, 0, 1);
    // q = 1
    vq_mfma_top2<<<MTOK / 32, 256, 0, stream>>>(xr, cbh + (size_t)NTOK * 512, cbl + (size_t)NTOK * 512,
                                                c2 + NTOK, r2, keys + MTOK, fc + 1, flag + MTOK);
    vq_rescue<<<1024, 256, 0, stream>>>(xr, cb1p, c2 + NTOK, r2, fc + 1, flag + MTOK, keys + MTOK);
    vq_apply<<<MTOK / 4, 256, 0, stream>>>(cb1p, keys + MTOK, xr, r2, idxf, idxi, slots, 1, 0);

    // quantized output [B,512,408]
    quant_out_kernel<<<dim3(NB, 7, 4), 256, 0, stream>>>(cbs, cb1p, idxi, qout);

    // decoder: d1 from code tables, then convT2, then final conv + recon
    d1_gather_kernel<<<(MTOK * 128) / 256, 256, 0, stream>>>(P0, P1, idxi, bx1, h1);
    gemm_nt<<<dim3(M2TOK / 128, 2), 256, 0, stream>>>(h1, Bd2, bx2, xr, M2TOK, 128, 64, 0, 2, 1);
    dec_final_kernel<<<MOUT / 256, 256, 0, stream>>>(xr, Wd3, bd3, img, out0, slots);

    finalize_kernel<<<1, 256, 0, stream>>>(slots, oscal);
}

// Round 9
// 1618.690 us; speedup vs baseline: 2.3525x; 2.3525x over previous
//
#include <hip/hip_runtime.h>

// ---------------- problem constants ----------------
#define NB    256
#define TLEN  1632
#define HIDC  64
#define CBD   512
#define NTOK  1024
#define T2L   816
#define T4L   408
#define MTOK  (NB*T4L)     // 104448
#define M2TOK (NB*T2L)     // 208896
#define MOUT  (NB*TLEN)    // 417792
#define TAU   0.05f

// d_out flat offsets (floats)
#define DO_OUT    ((size_t)0)
#define DO_RECON  ((size_t)417792)
#define DO_IDX    ((size_t)417795)
#define DO_QUANT  ((size_t)626691)

typedef unsigned short u16;
typedef __attribute__((ext_vector_type(8))) short short8;
typedef __attribute__((ext_vector_type(4))) float f32x4;

// ---------------- workspace layout (float units) ----------------
static constexpr size_t OFF_XR  = 0;                         // MTOK*512 f32
static constexpr size_t OFF_H1  = OFF_XR + (size_t)MTOK*512;
static constexpr size_t OFF_H2  = OFF_H1 + (size_t)NB*T2L*64;
static constexpr size_t OFF_BE2 = OFF_H2 + (size_t)NB*T4L*64;
static constexpr size_t OFF_BD1 = OFF_BE2 + 8192;
static constexpr size_t OFF_BD2 = OFF_BD1 + 65536;
static constexpr size_t OFF_BX1 = OFF_BD2 + 8192;
static constexpr size_t OFF_BX2 = OFF_BX1 + 128;
static constexpr size_t OFF_ZB  = OFF_BX2 + 128;
static constexpr size_t OFF_C2  = OFF_ZB + 128;
static constexpr size_t OFF_R2  = OFF_C2 + 2048;
static constexpr size_t OFF_SLOT= OFF_R2 + MTOK;
static constexpr size_t OFF_IDXI= OFF_SLOT + 1536;
static constexpr size_t OFF_KEYS= OFF_IDXI + (size_t)MTOK*2;
static constexpr size_t OFF_FC  = OFF_KEYS + (size_t)MTOK*4;
static constexpr size_t OFF_FLAG= OFF_FC + 4;
static constexpr size_t OFF_CBH = OFF_FLAG + (size_t)MTOK*2; // 2048*512 u16
static constexpr size_t OFF_CBL = OFF_CBH + 524288;
static constexpr size_t OFF_P0  = OFF_CBL + 524288;
static constexpr size_t OFF_P1  = OFF_P0 + 131072;
static constexpr size_t OFF_PAIRS = OFF_P1 + 131072;         // MTOK*8 u64 = MTOK*16 f

// ---------------- helpers ----------------
__device__ inline unsigned long long shfl_xor_u64_w16(unsigned long long v, int m) {
    unsigned lo = (unsigned)v, hi = (unsigned)(v >> 32);
    lo = __shfl_xor(lo, m, 16);
    hi = __shfl_xor(hi, m, 16);
    return (((unsigned long long)hi) << 32) | lo;
}
__device__ inline unsigned long long packkey(float d, int n) {
    unsigned u = __float_as_uint(d);
    u = (u & 0x80000000u) ? ~u : (u | 0x80000000u);
    return (((unsigned long long)u) << 32) | (unsigned)n;
}
__device__ inline float unpackd(unsigned long long k) {
    unsigned u = (unsigned)(k >> 32);
    u = (u & 0x80000000u) ? (u & 0x7fffffffu) : ~u;
    return __uint_as_float(u);
}
__device__ inline void merge2(unsigned long long& k1, unsigned long long& k2,
                              unsigned long long o1, unsigned long long o2) {
    unsigned long long n1 = (k1 < o1) ? k1 : o1;
    unsigned long long hi = (k1 < o1) ? o1 : k1;
    unsigned long long cand = (k1 <= o1) ? k2 : o2;
    unsigned long long n2 = (hi < cand) ? hi : cand;
    k1 = n1; k2 = n2;
}
__device__ inline void split4(float4 v, uint2& h, uint2& l) {
    unsigned b0 = __float_as_uint(v.x), b1 = __float_as_uint(v.y),
             b2 = __float_as_uint(v.z), b3 = __float_as_uint(v.w);
    float l0 = v.x - __uint_as_float(b0 & 0xFFFF0000u);
    float l1 = v.y - __uint_as_float(b1 & 0xFFFF0000u);
    float l2 = v.z - __uint_as_float(b2 & 0xFFFF0000u);
    float l3 = v.w - __uint_as_float(b3 & 0xFFFF0000u);
    h.x = (b0 >> 16) | (b1 & 0xFFFF0000u);
    h.y = (b2 >> 16) | (b3 & 0xFFFF0000u);
    l.x = (__float_as_uint(l0) >> 16) | (__float_as_uint(l1) & 0xFFFF0000u);
    l.y = (__float_as_uint(l2) >> 16) | (__float_as_uint(l3) & 0xFFFF0000u);
}

// ---------------- weight prep ----------------
__global__ void prep_kernel(const float* __restrict__ We2, const float* __restrict__ Wtd1,
                            const float* __restrict__ Wtd2, const float* __restrict__ bd1,
                            const float* __restrict__ bd2,
                            float* __restrict__ Be2, float* __restrict__ Bd1,
                            float* __restrict__ Bd2, float* __restrict__ bx1, float* __restrict__ bx2) {
    int i = blockIdx.x * blockDim.x + threadIdx.x;
    int stride = gridDim.x * blockDim.x;
    for (int x = i; x < 64 * 128; x += stride) {
        int c = x >> 7, k = x & 127;
        Be2[x] = We2[c * 128 + ((k & 63) << 1) + (k >> 6)];
    }
    for (int x = i; x < 128 * 512; x += stride) {
        int n = x >> 9, k = x & 511;
        Bd1[x] = Wtd1[k * 128 + n];
    }
    for (int x = i; x < 128 * 64; x += stride) {
        int n = x >> 6, k = x & 63;
        Bd2[x] = Wtd2[k * 128 + n];
    }
    for (int x = i; x < 128; x += stride) { bx1[x] = bd1[x >> 1]; bx2[x] = bd2[x >> 1]; }
}

// ---------------- codebook split to planar bf16 hi/lo ----------------
__global__ void split_cb_kernel(const float* __restrict__ cbs, u16* __restrict__ cbh, u16* __restrict__ cbl) {
    size_t t = (size_t)blockIdx.x * 256 + threadIdx.x;
    float4 v = *(const float4*)(cbs + t * 4);
    uint2 h, l; split4(v, h, l);
    *(uint2*)&cbh[t * 4] = h;
    *(uint2*)&cbl[t * 4] = l;
}

// ---------------- row sum-of-squares ----------------
__global__ void rownorm_kernel(const float* __restrict__ X, float* __restrict__ out, int rows) {
    int w = (blockIdx.x * blockDim.x + threadIdx.x) >> 6;
    int lane = threadIdx.x & 63;
    if (w >= rows) return;
    const float* r = X + (size_t)w * 512;
    float4 a = *(const float4*)(r + lane * 8);
    float4 b = *(const float4*)(r + lane * 8 + 4);
    float s = a.x*a.x + a.y*a.y + a.z*a.z + a.w*a.w + b.x*b.x + b.y*b.y + b.z*b.z + b.w*b.w;
    #pragma unroll
    for (int o = 32; o > 0; o >>= 1) s += __shfl_down(s, o, 64);
    if (lane == 0) out[w] = s;
}

// ---------------- encoder conv1 ----------------
__global__ void enc1_kernel(const float* __restrict__ img, const float* __restrict__ W,
                            const float* __restrict__ bias, float* __restrict__ h1) {
    int idx = blockIdx.x * 256 + threadIdx.x;
    int c = idx & 63;
    int t = (idx >> 6) % T2L;
    int b = idx / (64 * T2L);
    float v = W[c * 2] * img[(size_t)b * TLEN + 2 * t] +
              W[c * 2 + 1] * img[(size_t)b * TLEN + 2 * t + 1] + bias[c];
    h1[idx] = fmaxf(v, 0.f);
}

// ---------------- generic NT SGEMM ----------------
__global__ __launch_bounds__(256) void gemm_nt(const float* __restrict__ A, const float* __restrict__ Bw,
                        const float* __restrict__ bias, float* __restrict__ C,
                        int M, int N, int K, int amode, int cmode, int relu) {
    __shared__ float As[32][132];
    __shared__ float Bs[32][68];
    int m0 = blockIdx.x * 128;
    int n0 = blockIdx.y * 64;
    int tid = threadIdx.x;
    int tx = tid & 15;
    int ty = tid >> 4;
    float acc[8][4];
    #pragma unroll
    for (int i = 0; i < 8; ++i)
        #pragma unroll
        for (int j = 0; j < 4; ++j) acc[i][j] = 0.f;

    for (int k0 = 0; k0 < K; k0 += 32) {
        #pragma unroll
        for (int i = 0; i < 4; ++i) {
            int idx = tid + i * 256;
            int row = idx >> 3;
            int kq = idx & 7;
            int m = m0 + row;
            size_t base;
            if (amode == 0) base = (size_t)m * K;
            else            base = (size_t)(((m / T4L) * T2L + 2 * (m % T4L)) * 64);
            float4 v = *(const float4*)(A + base + k0 + kq * 4);
            int kk = kq * 4;
            As[kk + 0][row] = v.x; As[kk + 1][row] = v.y;
            As[kk + 2][row] = v.z; As[kk + 3][row] = v.w;
        }
        #pragma unroll
        for (int i = 0; i < 2; ++i) {
            int idx = tid + i * 256;
            int row = idx >> 3;
            int kq = idx & 7;
            float4 v = *(const float4*)(Bw + (size_t)(n0 + row) * K + k0 + kq * 4);
            int kk = kq * 4;
            Bs[kk + 0][row] = v.x; Bs[kk + 1][row] = v.y;
            Bs[kk + 2][row] = v.z; Bs[kk + 3][row] = v.w;
        }
        __syncthreads();
        #pragma unroll
        for (int kk = 0; kk < 32; ++kk) {
            float a[8], bf[4];
            float4 a0 = *(const float4*)&As[kk][ty * 8];
            float4 a1 = *(const float4*)&As[kk][ty * 8 + 4];
            a[0]=a0.x; a[1]=a0.y; a[2]=a0.z; a[3]=a0.w;
            a[4]=a1.x; a[5]=a1.y; a[6]=a1.z; a[7]=a1.w;
            float4 b0 = *(const float4*)&Bs[kk][tx * 4];
            bf[0]=b0.x; bf[1]=b0.y; bf[2]=b0.z; bf[3]=b0.w;
            #pragma unroll
            for (int i = 0; i < 8; ++i)
                #pragma unroll
                for (int j = 0; j < 4; ++j) acc[i][j] += a[i] * bf[j];
        }
        __syncthreads();
    }
    #pragma unroll
    for (int i = 0; i < 8; ++i) {
        int m = m0 + ty * 8 + i;
        if (cmode == 0) {
            float4 v;
            v.x = acc[i][0] + bias[n0 + tx * 4 + 0];
            v.y = acc[i][1] + bias[n0 + tx * 4 + 1];
            v.z = acc[i][2] + bias[n0 + tx * 4 + 2];
            v.w = acc[i][3] + bias[n0 + tx * 4 + 3];
            if (relu) { v.x=fmaxf(v.x,0.f); v.y=fmaxf(v.y,0.f); v.z=fmaxf(v.z,0.f); v.w=fmaxf(v.w,0.f); }
            *(float4*)(C + (size_t)m * N + n0 + tx * 4) = v;
        } else {
            int Tin = T2L;
            int Texp = 2 * Tin;
            int bb = m / Tin, t = m % Tin;
            #pragma unroll
            for (int j = 0; j < 4; ++j) {
                int n = n0 + tx * 4 + j;
                float v = acc[i][j] + bias[n];
                if (relu) v = fmaxf(v, 0.f);
                size_t off = (size_t)((bb * Texp + 2 * t + (n & 1)) * 64 + (n >> 1));
                C[off] = v;
            }
        }
    }
}

// ---------------- VQ: block 128(M)x256(N), wave 64x128, split-bf16 MFMA ----------------
// Per-block top-2 -> pairs[m*8 + bx*2]; global merge in vq_reduce (grid has 4 N-blocks!).
__global__ __launch_bounds__(256, 2) void vq_bf16_top2(
    const float* __restrict__ A, const u16* __restrict__ cbh, const u16* __restrict__ cbl,
    const float* __restrict__ c2, const float* __restrict__ r2,
    unsigned long long* __restrict__ pairs)
{
    __shared__ u16 Ah[128 * 40], Al[128 * 40];
    __shared__ u16 Bh[256 * 40], Bl[256 * 40];
    int tid = threadIdx.x;
    int n0 = blockIdx.x * 256, m0 = blockIdx.y * 128;
    int lane = tid & 63, wid = tid >> 6;
    int lm = lane & 15, quad = lane >> 4;
    int wm = wid >> 1, wn = wid & 1;

    f32x4 acc[4][8];
    #pragma unroll
    for (int i = 0; i < 4; ++i)
        #pragma unroll
        for (int j = 0; j < 8; ++j) acc[i][j] = (f32x4){0.f, 0.f, 0.f, 0.f};

    for (int k0 = 0; k0 < 512; k0 += 32) {
        float4 av[4];
        int ar[4], acq[4];
        #pragma unroll
        for (int i = 0; i < 4; ++i) {
            int idx = tid + i * 256;
            ar[i] = idx >> 3; acq[i] = idx & 7;
            av[i] = *(const float4*)(A + (size_t)(m0 + ar[i]) * 512 + k0 + acq[i] * 4);
        }
        short8 bv[8];
        int br[8], bcc[8], bpl[8];
        #pragma unroll
        for (int i = 0; i < 8; ++i) {
            int idx = tid + i * 256;
            br[i] = idx >> 3; int sub = idx & 7;
            bcc[i] = sub & 3; bpl[i] = sub >> 2;
            const u16* src = bpl[i] ? cbl : cbh;
            bv[i] = *(const short8*)(src + (size_t)(n0 + br[i]) * 512 + k0 + bcc[i] * 8);
        }
        __syncthreads();
        #pragma unroll
        for (int i = 0; i < 4; ++i) {
            uint2 h, l; split4(av[i], h, l);
            *(uint2*)&Ah[ar[i] * 40 + acq[i] * 4] = h;
            *(uint2*)&Al[ar[i] * 40 + acq[i] * 4] = l;
        }
        #pragma unroll
        for (int i = 0; i < 8; ++i) {
            u16* dst = bpl[i] ? Bl : Bh;
            *(short8*)&dst[br[i] * 40 + bcc[i] * 8] = bv[i];
        }
        __syncthreads();
        short8 ah[4], al_[4];
        #pragma unroll
        for (int mt = 0; mt < 4; ++mt) {
            int r = wm * 64 + mt * 16 + lm;
            ah[mt]  = *(const short8*)&Ah[r * 40 + quad * 8];
            al_[mt] = *(const short8*)&Al[r * 40 + quad * 8];
        }
        #pragma unroll
        for (int nt = 0; nt < 8; ++nt) {
            int rn = wn * 128 + nt * 16 + lm;
            short8 bh = *(const short8*)&Bh[rn * 40 + quad * 8];
            short8 bl = *(const short8*)&Bl[rn * 40 + quad * 8];
            #pragma unroll
            for (int mt = 0; mt < 4; ++mt) {
                acc[mt][nt] = __builtin_amdgcn_mfma_f32_16x16x32_bf16(al_[mt], bh, acc[mt][nt], 0, 0, 0);
                acc[mt][nt] = __builtin_amdgcn_mfma_f32_16x16x32_bf16(ah[mt], bl, acc[mt][nt], 0, 0, 0);
                acc[mt][nt] = __builtin_amdgcn_mfma_f32_16x16x32_bf16(ah[mt], bh, acc[mt][nt], 0, 0, 0);
            }
        }
    }
    // epilogue: per-token top-2 over this block's 256 codes
    float c2v[8];
    #pragma unroll
    for (int nt = 0; nt < 8; ++nt) c2v[nt] = c2[n0 + wn * 128 + nt * 16 + lm];

    __syncthreads();                       // done with LDS tiles; reuse Ah as scratch
    unsigned long long* scr = (unsigned long long*)Ah;   // [2 wn][128 tokens][2]
    #pragma unroll
    for (int mt = 0; mt < 4; ++mt) {
        #pragma unroll
        for (int rg = 0; rg < 4; ++rg) {
            int tl = wm * 64 + mt * 16 + quad * 4 + rg;
            float rr = r2[m0 + tl];
            unsigned long long k1 = ~0ull, k2 = ~0ull;
            #pragma unroll
            for (int nt = 0; nt < 8; ++nt) {
                float d = (rr - 2.0f * acc[mt][nt][rg]) + c2v[nt];
                unsigned long long k = packkey(d, n0 + wn * 128 + nt * 16 + lm);
                if (k < k1) { k2 = k1; k1 = k; } else if (k < k2) { k2 = k; }
            }
            #pragma unroll
            for (int s = 1; s < 16; s <<= 1) {
                unsigned long long o1 = shfl_xor_u64_w16(k1, s);
                unsigned long long o2 = shfl_xor_u64_w16(k2, s);
                merge2(k1, k2, o1, o2);
            }
            if (lm == 0) { scr[wn * 256 + tl * 2] = k1; scr[wn * 256 + tl * 2 + 1] = k2; }
        }
    }
    __syncthreads();
    if (tid < 128) {
        unsigned long long a1 = scr[tid * 2], a2 = scr[tid * 2 + 1];
        merge2(a1, a2, scr[256 + tid * 2], scr[256 + tid * 2 + 1]);
        size_t base = (size_t)(m0 + tid) * 8 + blockIdx.x * 2;
        pairs[base] = a1; pairs[base + 1] = a2;
    }
}

// ---------------- reduce: global top2 per token from 4 block-pairs ----------------
__global__ void vq_reduce(const unsigned long long* __restrict__ pairs,
                          unsigned long long* __restrict__ keybuf,
                          int* __restrict__ fc, int* __restrict__ flaglist) {
    int m = blockIdx.x * 256 + threadIdx.x;
    const unsigned long long* p = pairs + (size_t)m * 8;
    unsigned long long k1 = ~0ull, k2 = ~0ull;
    #pragma unroll
    for (int i = 0; i < 8; ++i) {
        unsigned long long k = p[i];
        if (k < k1) { k2 = k1; k1 = k; } else if (k < k2) { k2 = k; }
    }
    keybuf[m] = k1;
    if (unpackd(k2) - unpackd(k1) < TAU) {
        int pos = atomicAdd(fc, 1);
        flaglist[pos] = m;
    }
}

// ---------------- rescue: exact fp32 argmin for flagged tokens ----------------
__global__ void vq_rescue(const float* __restrict__ xr, const float* __restrict__ cb,
                          const float* __restrict__ c2, const float* __restrict__ r2,
                          const int* __restrict__ fc, const int* __restrict__ flaglist,
                          unsigned long long* __restrict__ keybuf) {
    __shared__ unsigned long long red[4];
    int cnt = *fc;
    int lane = threadIdx.x & 63, wid = threadIdx.x >> 6;
    for (int f = blockIdx.x; f < cnt; f += gridDim.x) {
        int m = flaglist[f];
        float4 rv0 = *(const float4*)(xr + (size_t)m * 512 + lane * 8);
        float4 rv1 = *(const float4*)(xr + (size_t)m * 512 + lane * 8 + 4);
        float rr = r2[m];
        unsigned long long best = ~0ull;
        for (int c = wid * 256; c < wid * 256 + 256; ++c) {
            const float* cp = cb + (size_t)c * 512 + lane * 8;
            float4 c0 = *(const float4*)cp;
            float4 c1 = *(const float4*)(cp + 4);
            float p = rv0.x*c0.x + rv0.y*c0.y + rv0.z*c0.z + rv0.w*c0.w
                    + rv1.x*c1.x + rv1.y*c1.y + rv1.z*c1.z + rv1.w*c1.w;
            #pragma unroll
            for (int s = 1; s < 64; s <<= 1) p += __shfl_xor(p, s, 64);
            unsigned long long k = packkey((rr - 2.0f * p) + c2[c], c);
            if (k < best) best = k;
        }
        if (lane == 0) red[wid] = best;
        __syncthreads();
        if (threadIdx.x == 0) {
            unsigned long long b = red[0];
            if (red[1] < b) b = red[1];
            if (red[2] < b) b = red[2];
            if (red[3] < b) b = red[3];
            keybuf[m] = b;
        }
        __syncthreads();
    }
}

// ---------------- VQ apply (wave per token) ----------------
__global__ void vq_apply(const float* __restrict__ cb, const unsigned long long* __restrict__ keybuf,
                         float* __restrict__ R, float* __restrict__ r2,
                         float* __restrict__ idx_f, int* __restrict__ idx_i,
                         float* __restrict__ slots, int q, int write_r) {
    int tid = threadIdx.x;
    int lane = tid & 63;
    int m = blockIdx.x * 4 + (tid >> 6);
    unsigned idx = (unsigned)(keybuf[m] & 0xFFFFFFFFull);
    const float* c = cb + (size_t)idx * 512 + lane * 8;
    float* r = R + (size_t)m * 512 + lane * 8;
    float4 r0 = *(const float4*)r, r1 = *(const float4*)(r + 4);
    float4 c0 = *(const float4*)c, c1 = *(const float4*)(c + 4);
    r0.x -= c0.x; r0.y -= c0.y; r0.z -= c0.z; r0.w -= c0.w;
    r1.x -= c1.x; r1.y -= c1.y; r1.z -= c1.z; r1.w -= c1.w;
    if (write_r) { *(float4*)r = r0; *(float4*)(r + 4) = r1; }
    float s = r0.x*r0.x + r0.y*r0.y + r0.z*r0.z + r0.w*r0.w
            + r1.x*r1.x + r1.y*r1.y + r1.z*r1.z + r1.w*r1.w;
    #pragma unroll
    for (int o = 32; o > 0; o >>= 1) s += __shfl_down(s, o, 64);
    if (lane == 0) {
        if (write_r) r2[m] = s;
        atomicAdd(&slots[512 + q * 512 + (m & 511)], s);
        idx_f[(size_t)m * 2 + q] = (float)idx;
        idx_i[m * 2 + q] = (int)idx;
    }
}

// ---------------- quantized output (channel-major) via LDS transpose ----------------
__global__ void quant_out_kernel(const float* __restrict__ cb0, const float* __restrict__ cb1,
                                 const int* __restrict__ idxi, float* __restrict__ out4) {
    __shared__ float buf[64][129];
    __shared__ int i0s[64], i1s[64];
    int b = blockIdx.x;
    int t0 = blockIdx.y * 64;
    int c0 = blockIdx.z * 128;
    int tid = threadIdx.x;
    if (tid < 64) {
        int t = t0 + tid;
        int i0 = 0, i1 = 0;
        if (t < T4L) { i0 = idxi[(b * T4L + t) * 2]; i1 = idxi[(b * T4L + t) * 2 + 1]; }
        i0s[tid] = i0; i1s[tid] = i1;
    }
    __syncthreads();
    int cl = tid & 127, th = tid >> 7;
    for (int t = th; t < 64; t += 2) {
        if (t0 + t < T4L)
            buf[t][cl] = cb0[(size_t)i0s[t] * 512 + c0 + cl] + cb1[(size_t)i1s[t] * 512 + c0 + cl];
    }
    __syncthreads();
    int lane = tid & 63, ch = tid >> 6;
    for (int cc = ch; cc < 128; cc += 4) {
        int t = t0 + lane;
        if (t < T4L) out4[((size_t)b * 512 + c0 + cc) * T4L + t] = buf[lane][cc];
    }
}

// ---------------- decoder stage-1 via code tables ----------------
__global__ void d1_gather_kernel(const float* __restrict__ P0, const float* __restrict__ P1,
                                 const int* __restrict__ idxi, const float* __restrict__ bx1,
                                 float* __restrict__ d1) {
    int x = blockIdx.x * 256 + threadIdx.x;
    int n = x & 127;
    int m = x >> 7;
    int b = m / T4L, t = m % T4L;
    int i0 = idxi[m * 2], i1 = idxi[m * 2 + 1];
    float v = P0[i0 * 128 + n] + P1[i1 * 128 + n] + bx1[n];
    v = fmaxf(v, 0.f);
    d1[((size_t)(b * T2L + 2 * t + (n & 1))) * 64 + (n >> 1)] = v;
}

// ---------------- final 1x1 conv + recon loss ----------------
__global__ void dec_final_kernel(const float* __restrict__ d2buf, const float* __restrict__ W,
                                 const float* __restrict__ bb, const float* __restrict__ img,
                                 float* __restrict__ out, float* __restrict__ slots) {
    __shared__ float red[256];
    int tok = blockIdx.x * 256 + threadIdx.x;
    float acc = bb[0];
    const float* row = d2buf + (size_t)tok * 64;
    #pragma unroll
    for (int i = 0; i < 16; ++i) {
        float4 v = *(const float4*)(row + i * 4);
        float4 w = *(const float4*)(W + i * 4);
        acc += v.x * w.x + v.y * w.y + v.z * w.z + v.w * w.w;
    }
    out[tok] = acc;
    float d = img[tok] - acc;
    red[threadIdx.x] = d * d; __syncthreads();
    for (int s = 128; s > 0; s >>= 1) { if (threadIdx.x < s) red[threadIdx.x] += red[threadIdx.x + s]; __syncthreads(); }
    if (threadIdx.x == 0) atomicAdd(&slots[blockIdx.x & 511], red[0]);
}

// ---------------- finalize losses ----------------
__global__ void finalize_kernel(const float* __restrict__ slots, float* __restrict__ out_scalars) {
    __shared__ float red[256];
    int tid = threadIdx.x;
    for (int which = 0; which < 3; ++which) {
        float s = slots[which * 512 + tid] + slots[which * 512 + tid + 256];
        red[tid] = s; __syncthreads();
        for (int st = 128; st > 0; st >>= 1) { if (tid < st) red[tid] += red[tid + st]; __syncthreads(); }
        if (tid == 0) {
            float denom = (which == 0) ? (float)MOUT : (float)((size_t)MTOK * 512);
            out_scalars[which] = red[0] / denom;
        }
        __syncthreads();
    }
}

// ---------------- launch ----------------
extern "C" void kernel_launch(void* const* d_in, const int* in_sizes, int n_in,
                              void* d_out, int out_size, void* d_ws, size_t ws_size,
                              hipStream_t stream) {
    const float* img  = (const float*)d_in[0];
    const float* We1  = (const float*)d_in[1];
    const float* be1  = (const float*)d_in[2];
    const float* We2  = (const float*)d_in[3];
    const float* be2  = (const float*)d_in[4];
    const float* We3  = (const float*)d_in[5];
    const float* be3  = (const float*)d_in[6];
    const float* cbs  = (const float*)d_in[7];
    const float* Wtd1 = (const float*)d_in[8];
    const float* bd1  = (const float*)d_in[9];
    const float* Wtd2 = (const float*)d_in[10];
    const float* bd2  = (const float*)d_in[11];
    const float* Wd3  = (const float*)d_in[12];
    const float* bd3  = (const float*)d_in[13];

    float* w = (float*)d_ws;
    float* xr   = w + OFF_XR;
    float* h1   = w + OFF_H1;
    float* h2   = w + OFF_H2;
    float* Be2  = w + OFF_BE2;
    float* Bd1  = w + OFF_BD1;
    float* Bd2  = w + OFF_BD2;
    float* bx1  = w + OFF_BX1;
    float* bx2  = w + OFF_BX2;
    float* zerob= w + OFF_ZB;
    float* c2   = w + OFF_C2;
    float* r2   = w + OFF_R2;
    float* slots= w + OFF_SLOT;
    int*   idxi = (int*)(w + OFF_IDXI);
    unsigned long long* keys = (unsigned long long*)(w + OFF_KEYS);
    int*   fc   = (int*)(w + OFF_FC);
    int*   flag = (int*)(w + OFF_FLAG);
    u16*   cbh  = (u16*)(w + OFF_CBH);
    u16*   cbl  = (u16*)(w + OFF_CBL);
    float* P0   = w + OFF_P0;
    float* P1   = w + OFF_P1;
    unsigned long long* pairs = (unsigned long long*)(w + OFF_PAIRS);

    float* outp = (float*)d_out;
    float* out0   = outp + DO_OUT;
    float* oscal  = outp + DO_RECON;
    float* idxf   = outp + DO_IDX;
    float* qout   = outp + DO_QUANT;

    hipMemsetAsync(slots, 0, 1536 * sizeof(float), stream);
    hipMemsetAsync(fc, 0, 2 * sizeof(int), stream);
    hipMemsetAsync(zerob, 0, 128 * sizeof(float), stream);

    prep_kernel<<<64, 256, 0, stream>>>(We2, Wtd1, Wtd2, bd1, bd2, Be2, Bd1, Bd2, bx1, bx2);
    split_cb_kernel<<<1024, 256, 0, stream>>>(cbs, cbh, cbl);
    rownorm_kernel<<<(2048 * 64) / 256, 256, 0, stream>>>(cbs, c2, 2048);

    const float* cb1p = cbs + (size_t)NTOK * CBD;

    // decoder stage-1 code tables: P = cb . Bd1^T
    gemm_nt<<<dim3(8, 2), 256, 0, stream>>>(cbs,  Bd1, zerob, P0, 1024, 128, 512, 0, 0, 0);
    gemm_nt<<<dim3(8, 2), 256, 0, stream>>>(cb1p, Bd1, zerob, P1, 1024, 128, 512, 0, 0, 0);

    // encoder
    enc1_kernel<<<(NB * T2L * HIDC) / 256, 256, 0, stream>>>(img, We1, be1, h1);
    gemm_nt<<<dim3(MTOK / 128, 1), 256, 0, stream>>>(h1, Be2, be2, h2, MTOK, 64, 128, 1, 0, 1);
    gemm_nt<<<dim3(MTOK / 128, 8), 256, 0, stream>>>(h2, We3, be3, xr, MTOK, 512, 64, 0, 0, 0);
    rownorm_kernel<<<((size_t)MTOK * 64) / 256, 256, 0, stream>>>(xr, r2, MTOK);

    // residual VQ, q = 0
    vq_bf16_top2<<<dim3(4, MTOK / 128), 256, 0, stream>>>(xr, cbh, cbl, c2, r2, pairs);
    vq_reduce<<<MTOK / 256, 256, 0, stream>>>(pairs, keys, fc + 0, flag);
    vq_rescue<<<1024, 256, 0, stream>>>(xr, cbs, c2, r2, fc + 0, flag, keys);
    vq_apply<<<MTOK / 4, 256, 0, stream>>>(cbs, keys, xr, r2, idxf, idxi, slots, 0, 1);
    // q = 1
    vq_bf16_top2<<<dim3(4, MTOK / 128), 256, 0, stream>>>(xr, cbh + (size_t)NTOK * 512, cbl + (size_t)NTOK * 512,
                                                          c2 + NTOK, r2, pairs);
    vq_reduce<<<MTOK / 256, 256, 0, stream>>>(pairs, keys + MTOK, fc + 1, flag + MTOK);
    vq_rescue<<<1024, 256, 0, stream>>>(xr, cb1p, c2 + NTOK, r2, fc + 1, flag + MTOK, keys + MTOK);
    vq_apply<<<MTOK / 4, 256, 0, stream>>>(cb1p, keys + MTOK, xr, r2, idxf, idxi, slots, 1, 0);

    // quantized output [B,512,408]
    quant_out_kernel<<<dim3(NB, 7, 4), 256, 0, stream>>>(cbs, cb1p, idxi, qout);

    // decoder
    d1_gather_kernel<<<(MTOK * 128) / 256, 256, 0, stream>>>(P0, P1, idxi, bx1, h1);
    gemm_nt<<<dim3(M2TOK / 128, 2), 256, 0, stream>>>(h1, Bd2, bx2, xr, M2TOK, 128, 64, 0, 2, 1);
    dec_final_kernel<<<MOUT / 256, 256, 0, stream>>>(xr, Wd3, bd3, img, out0, slots);

    finalize_kernel<<<1, 256, 0, stream>>>(slots, oscal);
}